// Round 5
// baseline (167.281 us; speedup 1.0000x reference)
//
#include <hip/hip_runtime.h>
#include <cstdint>
#include <cstddef>

#define D 64

typedef float f32x4 __attribute__((ext_vector_type(4)));
typedef uint32_t u32x4 __attribute__((ext_vector_type(4)));

// round-to-nearest-even fp32 -> bf16 (bits in low 16)
__device__ __forceinline__ uint32_t rne_bf16(float f) {
    uint32_t x = __float_as_uint(f);
    return (x + 0x7fffu + ((x >> 16) & 1u)) >> 16;
}
__device__ __forceinline__ float bf16lo(uint32_t u) { return __uint_as_float(u << 16); }
__device__ __forceinline__ float bf16hi(uint32_t u) { return __uint_as_float(u & 0xffff0000u); }

// Kernel 1: Xh = packed bf16(X). Row = 32 u32 (128 B); u32 k packs features
// (2k, 2k+1). Pure streaming: one float4 -> uint2 per thread, grid-strided.
__global__ __launch_bounds__(256) void cast_kernel(
    const float* __restrict__ X, uint32_t* __restrict__ Xh, long n4)
{
    long i = (long)blockIdx.x * blockDim.x + threadIdx.x;
    const long stride = (long)gridDim.x * blockDim.x;
    for (; i < n4; i += stride) {
        f32x4 v = __builtin_nontemporal_load((const f32x4*)X + i);
        uint2 o;
        o.x = rne_bf16(v.x) | (rne_bf16(v.y) << 16);
        o.y = rne_bf16(v.z) | (rne_bf16(v.w) << 16);
        ((uint2*)Xh)[i] = o;   // normal store: Xh is re-read by gather
    }
}

// Kernel 2: out[r] = (sum_{e in row r} Xh[ci[e]]) @ W.
// Grid-strided one wave per row. o = lane>>3 (edge slot 0..7), p = lane&7
// (feature octet: uint4 = 8 bf16 features). 8 edges per load instruction,
// 2-deep unroll = 16 edges in flight. After shfl_xor(8/16/32) butterfly all
// lanes hold the aggregate; GEMM = 64 readlane+FMA against VGPR-resident
// W column (preloaded once per wave).
__global__ __launch_bounds__(256, 4) void gather_gemm_kernel(
    const uint32_t* __restrict__ Xh, const float* __restrict__ W,
    const int* __restrict__ rp, const int* __restrict__ ci,
    float* __restrict__ out, int n_nodes)
{
    const int lane = threadIdx.x & 63;
    const int o = lane >> 3;
    const int p = lane & 7;

    float wcol[D];
#pragma unroll
    for (int d = 0; d < D; ++d) wcol[d] = W[d * D + lane];

    const int gwave = (int)((blockIdx.x * blockDim.x + threadIdx.x) >> 6);
    const int nwaves = (int)((gridDim.x * blockDim.x) >> 6);

    for (int row = gwave; row < n_nodes; row += nwaves) {
        const int e0 = rp[row];
        const int e1 = rp[row + 1];

        float r[8], s[8];
#pragma unroll
        for (int j = 0; j < 8; ++j) { r[j] = 0.f; s[j] = 0.f; }

        int e = e0;
        for (; e + 16 <= e1; e += 16) {
            const int i0 = ci[e + o];
            const int i1 = ci[e + 8 + o];
            const u32x4 u = *(const u32x4*)(Xh + (size_t)i0 * 32 + p * 4);
            const u32x4 v = *(const u32x4*)(Xh + (size_t)i1 * 32 + p * 4);
#pragma unroll
            for (int k = 0; k < 4; ++k) {
                r[2 * k]     += bf16lo(u[k]);
                r[2 * k + 1] += bf16hi(u[k]);
                s[2 * k]     += bf16lo(v[k]);
                s[2 * k + 1] += bf16hi(v[k]);
            }
        }
        if (e + 8 <= e1) {
            const int i0 = ci[e + o];
            const u32x4 u = *(const u32x4*)(Xh + (size_t)i0 * 32 + p * 4);
#pragma unroll
            for (int k = 0; k < 4; ++k) {
                r[2 * k]     += bf16lo(u[k]);
                r[2 * k + 1] += bf16hi(u[k]);
            }
            e += 8;
        }
        const int rem = e1 - e;  // 0..7
        if (o < rem) {
            const int i0 = ci[e + o];
            const u32x4 u = *(const u32x4*)(Xh + (size_t)i0 * 32 + p * 4);
#pragma unroll
            for (int k = 0; k < 4; ++k) {
                s[2 * k]     += bf16lo(u[k]);
                s[2 * k + 1] += bf16hi(u[k]);
            }
        }

#pragma unroll
        for (int j = 0; j < 8; ++j) r[j] += s[j];
        // butterfly across the 8 edge slots: all lanes end with full sums
#pragma unroll
        for (int j = 0; j < 8; ++j) {
            r[j] += __shfl_xor(r[j], 8, 64);
            r[j] += __shfl_xor(r[j], 16, 64);
            r[j] += __shfl_xor(r[j], 32, 64);
        }
        // lane with index (d>>3) holds feature d in r[d&7] (its p == d>>3)

        float g0 = 0.f, g1 = 0.f, g2 = 0.f, g3 = 0.f;
#pragma unroll
        for (int d = 0; d < D; d += 4) {
            g0 += __int_as_float(__builtin_amdgcn_readlane(__float_as_int(r[(d + 0) & 7]), (d + 0) >> 3)) * wcol[d + 0];
            g1 += __int_as_float(__builtin_amdgcn_readlane(__float_as_int(r[(d + 1) & 7]), (d + 1) >> 3)) * wcol[d + 1];
            g2 += __int_as_float(__builtin_amdgcn_readlane(__float_as_int(r[(d + 2) & 7]), (d + 2) >> 3)) * wcol[d + 2];
            g3 += __int_as_float(__builtin_amdgcn_readlane(__float_as_int(r[(d + 3) & 7]), (d + 3) >> 3)) * wcol[d + 3];
        }
        const float g = (g0 + g1) + (g2 + g3);
        __builtin_nontemporal_store(g, out + (size_t)row * D + lane);  // 256B/wave coalesced
    }
}

// Fallback if ws can't hold Xh: fused per-row aggregate + shfl-broadcast GEMM.
__global__ __launch_bounds__(256) void fused_kernel(
    const float* __restrict__ X, const float* __restrict__ W,
    const int* __restrict__ rp, const int* __restrict__ ci,
    float* __restrict__ out, int n_nodes)
{
    __shared__ float Wl[D * D];
    for (int i = threadIdx.x; i < D * D; i += 256) Wl[i] = W[i];
    __syncthreads();

    const int lane = threadIdx.x & 63;
    const int gwave = (int)((blockIdx.x * blockDim.x + threadIdx.x) >> 6);
    const int nwaves = (int)((gridDim.x * blockDim.x) >> 6);

    for (int row = gwave; row < n_nodes; row += nwaves) {
        int e0 = rp[row];
        int e1 = rp[row + 1];
        float acc = 0.f;
        for (int e = e0; e < e1; ++e) acc += X[ci[e] * D + lane];
        float sum = 0.f;
#pragma unroll
        for (int d = 0; d < D; ++d) {
            float a = __shfl(acc, d, 64);
            sum += a * Wl[d * D + lane];
        }
        out[row * D + lane] = sum;
    }
}

extern "C" void kernel_launch(void* const* d_in, const int* in_sizes, int n_in,
                              void* d_out, int out_size, void* d_ws, size_t ws_size,
                              hipStream_t stream)
{
    const float* X  = (const float*)d_in[0];   // [n, 64]
    const float* W  = (const float*)d_in[1];   // [64, 64]
    const int*   rp = (const int*)d_in[2];     // [n+1]
    const int*   ci = (const int*)d_in[3];     // [n_edges]
    float* out = (float*)d_out;

    const int n_nodes = in_sizes[2] - 1;
    const size_t xh_bytes = (size_t)n_nodes * 32 * sizeof(uint32_t);

    if (ws_size >= xh_bytes) {
        uint32_t* Xh = (uint32_t*)d_ws;
        const long n4 = (long)n_nodes * (D / 4);           // float4s
        int cast_blocks = (int)((n4 + 255) / 256);
        if (cast_blocks > 6400) cast_blocks = 6400;
        cast_kernel<<<cast_blocks, 256, 0, stream>>>(X, Xh, n4);
        gather_gemm_kernel<<<2048, 256, 0, stream>>>(Xh, W, rp, ci, out, n_nodes);
    } else {
        fused_kernel<<<2048, 256, 0, stream>>>(X, W, rp, ci, out, n_nodes);
    }
}

// Round 6
// 154.357 us; speedup vs baseline: 1.0837x; 1.0837x over previous
//
#include <hip/hip_runtime.h>
#include <cstdint>
#include <cstddef>

#define D 64

typedef float  f32x4 __attribute__((ext_vector_type(4)));
typedef short  s16x8 __attribute__((ext_vector_type(8)));

// round-to-nearest-even fp32 -> bf16 (bits in low 16)
__device__ __forceinline__ uint32_t rne_bf16(float f) {
    uint32_t x = __float_as_uint(f);
    return (x + 0x7fffu + ((x >> 16) & 1u)) >> 16;
}
__device__ __forceinline__ float bf16lo(uint32_t u) { return __uint_as_float(u << 16); }
__device__ __forceinline__ float bf16hi(uint32_t u) { return __uint_as_float(u & 0xffff0000u); }

// Kernel 1: Xh = packed bf16(X). u32 t of a row packs features (2t, 2t+1).
__global__ __launch_bounds__(256) void cast_kernel(
    const float* __restrict__ X, uint32_t* __restrict__ Xh, long n4)
{
    long i = (long)blockIdx.x * blockDim.x + threadIdx.x;
    const long stride = (long)gridDim.x * blockDim.x;
    for (; i < n4; i += stride) {
        f32x4 v = __builtin_nontemporal_load((const f32x4*)X + i);
        uint2 o;
        o.x = rne_bf16(v.x) | (rne_bf16(v.y) << 16);
        o.y = rne_bf16(v.z) | (rne_bf16(v.w) << 16);
        ((uint2*)Xh)[i] = o;
    }
}

// Kernel 2: Agg[r] = bf16( sum_{e in row r} Xh[ci[e]] ).
// TWO rows per wave, interleaved issue for 2x memory-level parallelism on
// short rows. o = lane>>4 (edge slot 0..3), p = lane&15 (feature quad:
// uint2 = 4 bf16). 4 edges/load-instr, 8 edges/row/iter, 2 rows in flight.
__global__ __launch_bounds__(256) void gather2_kernel(
    const uint32_t* __restrict__ Xh, const int* __restrict__ rp,
    const int* __restrict__ ci, uint32_t* __restrict__ Agg, int n_nodes)
{
    const int lane = threadIdx.x & 63;
    const int o = lane >> 4;
    const int p = lane & 15;
    const int w = (int)((blockIdx.x * blockDim.x + threadIdx.x) >> 6);
    const int rowA = 2 * w;
    if (rowA >= n_nodes) return;
    const int rowB = rowA + 1;
    const bool hasB = rowB < n_nodes;

    int ea = rp[rowA];
    const int a1 = rp[rowA + 1];
    int eb = hasB ? rp[rowB] : 0;
    const int b1 = hasB ? rp[rowB + 1] : 0;

    float A0[4] = {0,0,0,0}, A1[4] = {0,0,0,0};
    float B0[4] = {0,0,0,0}, B1[4] = {0,0,0,0};

    for (;;) {
        const bool da = (ea + 8 <= a1);
        const bool db = (eb + 8 <= b1);
        if (!da && !db) break;
        int ia0, ia1, ib0, ib1;
        if (da) { ia0 = ci[ea + o]; ia1 = ci[ea + 4 + o]; }
        if (db) { ib0 = ci[eb + o]; ib1 = ci[eb + 4 + o]; }
        uint2 ua0, ua1, ub0, ub1;
        if (da) {
            ua0 = *(const uint2*)(Xh + (size_t)ia0 * 32 + p * 2);
            ua1 = *(const uint2*)(Xh + (size_t)ia1 * 32 + p * 2);
        }
        if (db) {
            ub0 = *(const uint2*)(Xh + (size_t)ib0 * 32 + p * 2);
            ub1 = *(const uint2*)(Xh + (size_t)ib1 * 32 + p * 2);
        }
        if (da) {
            A0[0] += bf16lo(ua0.x); A0[1] += bf16hi(ua0.x); A0[2] += bf16lo(ua0.y); A0[3] += bf16hi(ua0.y);
            A1[0] += bf16lo(ua1.x); A1[1] += bf16hi(ua1.x); A1[2] += bf16lo(ua1.y); A1[3] += bf16hi(ua1.y);
            ea += 8;
        }
        if (db) {
            B0[0] += bf16lo(ub0.x); B0[1] += bf16hi(ub0.x); B0[2] += bf16lo(ub0.y); B0[3] += bf16hi(ub0.y);
            B1[0] += bf16lo(ub1.x); B1[1] += bf16hi(ub1.x); B1[2] += bf16lo(ub1.y); B1[3] += bf16hi(ub1.y);
            eb += 8;
        }
    }

    {   // remainder: one 4-edge step per row
        const bool da = (ea + 4 <= a1);
        const bool db = (eb + 4 <= b1);
        int ia, ib; uint2 ua, ub;
        if (da) ia = ci[ea + o];
        if (db) ib = ci[eb + o];
        if (da) ua = *(const uint2*)(Xh + (size_t)ia * 32 + p * 2);
        if (db) ub = *(const uint2*)(Xh + (size_t)ib * 32 + p * 2);
        if (da) {
            A0[0] += bf16lo(ua.x); A0[1] += bf16hi(ua.x); A0[2] += bf16lo(ua.y); A0[3] += bf16hi(ua.y);
            ea += 4;
        }
        if (db) {
            B0[0] += bf16lo(ub.x); B0[1] += bf16hi(ub.x); B0[2] += bf16lo(ub.y); B0[3] += bf16hi(ub.y);
            eb += 4;
        }
    }
    {   // final 0..3 edges per row (divergent over o)
        const int ra = a1 - ea, rb = b1 - eb;
        const bool dal = (o < ra), dbl = (o < rb);
        int ia, ib; uint2 ua, ub;
        if (dal) ia = ci[ea + o];
        if (dbl) ib = ci[eb + o];
        if (dal) ua = *(const uint2*)(Xh + (size_t)ia * 32 + p * 2);
        if (dbl) ub = *(const uint2*)(Xh + (size_t)ib * 32 + p * 2);
        if (dal) {
            A1[0] += bf16lo(ua.x); A1[1] += bf16hi(ua.x); A1[2] += bf16lo(ua.y); A1[3] += bf16hi(ua.y);
        }
        if (dbl) {
            B1[0] += bf16lo(ub.x); B1[1] += bf16hi(ub.x); B1[2] += bf16lo(ub.y); B1[3] += bf16hi(ub.y);
        }
    }

    // reduce across the 4 edge slots; lanes 0..15 then hold full sums
#pragma unroll
    for (int j = 0; j < 4; ++j) {
        float va = A0[j] + A1[j];
        va += __shfl_xor(va, 16, 64);
        va += __shfl_xor(va, 32, 64);
        A0[j] = va;
        float vb = B0[j] + B1[j];
        vb += __shfl_xor(vb, 16, 64);
        vb += __shfl_xor(vb, 32, 64);
        B0[j] = vb;
    }
    if (lane < 16) {
        uint2 oa;
        oa.x = rne_bf16(A0[0]) | (rne_bf16(A0[1]) << 16);
        oa.y = rne_bf16(A0[2]) | (rne_bf16(A0[3]) << 16);
        *(uint2*)(Agg + (size_t)rowA * 32 + p * 2) = oa;
        if (hasB) {
            uint2 ob;
            ob.x = rne_bf16(B0[0]) | (rne_bf16(B0[1]) << 16);
            ob.y = rne_bf16(B0[2]) | (rne_bf16(B0[3]) << 16);
            *(uint2*)(Agg + (size_t)rowB * 32 + p * 2) = ob;
        }
    }
}

// Kernel 3: out = Agg(bf16) @ W via mfma_f32_16x16x32_bf16.
// One wave per 16-row tile (grid-strided). B-frags (W, all 4 col-tiles x
// 2 k-blocks) converted to bf16 and kept in VGPRs once per wave.
// A-frag: A[m=lane&15][k=q*8+j]; B-frag: B[k=q*8+j][n=lane&15];
// C/D: col=lane&15, row=q*4+reg  (q = lane>>4).
__global__ __launch_bounds__(256) void agg_gemm_kernel(
    const uint32_t* __restrict__ Agg, const float* __restrict__ W,
    float* __restrict__ out, int n_nodes)
{
    const int lane = threadIdx.x & 63;
    const int n = lane & 15;
    const int q = lane >> 4;

    s16x8 Bf[4][2];
#pragma unroll
    for (int c = 0; c < 4; ++c)
#pragma unroll
        for (int kb = 0; kb < 2; ++kb) {
            s16x8 b;
#pragma unroll
            for (int j = 0; j < 8; ++j) {
                const int k = kb * 32 + q * 8 + j;
                b[j] = (short)rne_bf16(W[k * D + c * 16 + n]);
            }
            Bf[c][kb] = b;
        }

    const int n_tiles = (n_nodes + 15) / 16;
    const int gwave = (int)((blockIdx.x * blockDim.x + threadIdx.x) >> 6);
    const int nwaves = (int)((gridDim.x * blockDim.x) >> 6);

    for (int t = gwave; t < n_tiles; t += nwaves) {
        const int m0 = t * 16;
        int arow = m0 + n;
        if (arow >= n_nodes) arow = n_nodes - 1;  // clamp (tail tile)
        const s16x8 A0 = *(const s16x8*)(Agg + (size_t)arow * 32 + q * 4);
        const s16x8 A1 = *(const s16x8*)(Agg + (size_t)arow * 32 + 16 + q * 4);

        f32x4 acc[4];
#pragma unroll
        for (int c = 0; c < 4; ++c) {
            f32x4 z = {0.f, 0.f, 0.f, 0.f};
            z = __builtin_amdgcn_mfma_f32_16x16x32_bf16(A0, Bf[c][0], z, 0, 0, 0);
            z = __builtin_amdgcn_mfma_f32_16x16x32_bf16(A1, Bf[c][1], z, 0, 0, 0);
            acc[c] = z;
        }
#pragma unroll
        for (int r = 0; r < 4; ++r) {
            const int ro = m0 + q * 4 + r;
            if (ro < n_nodes) {
#pragma unroll
                for (int c = 0; c < 4; ++c)
                    out[(size_t)ro * D + c * 16 + n] = acc[c][r];
            }
        }
    }
}

// Fallback if ws can't hold Xh+Agg: fused per-row aggregate + shfl GEMM.
__global__ __launch_bounds__(256) void fused_kernel(
    const float* __restrict__ X, const float* __restrict__ W,
    const int* __restrict__ rp, const int* __restrict__ ci,
    float* __restrict__ out, int n_nodes)
{
    __shared__ float Wl[D * D];
    for (int i = threadIdx.x; i < D * D; i += 256) Wl[i] = W[i];
    __syncthreads();

    const int lane = threadIdx.x & 63;
    const int gwave = (int)((blockIdx.x * blockDim.x + threadIdx.x) >> 6);
    const int nwaves = (int)((gridDim.x * blockDim.x) >> 6);

    for (int row = gwave; row < n_nodes; row += nwaves) {
        int e0 = rp[row];
        int e1 = rp[row + 1];
        float acc = 0.f;
        for (int e = e0; e < e1; ++e) acc += X[ci[e] * D + lane];
        float sum = 0.f;
#pragma unroll
        for (int d = 0; d < D; ++d) {
            float a = __shfl(acc, d, 64);
            sum += a * Wl[d * D + lane];
        }
        out[row * D + lane] = sum;
    }
}

extern "C" void kernel_launch(void* const* d_in, const int* in_sizes, int n_in,
                              void* d_out, int out_size, void* d_ws, size_t ws_size,
                              hipStream_t stream)
{
    const float* X  = (const float*)d_in[0];   // [n, 64]
    const float* W  = (const float*)d_in[1];   // [64, 64]
    const int*   rp = (const int*)d_in[2];     // [n+1]
    const int*   ci = (const int*)d_in[3];     // [n_edges]
    float* out = (float*)d_out;

    const int n_nodes = in_sizes[2] - 1;
    const size_t row_bytes = 32 * sizeof(uint32_t);           // 128 B bf16 row
    const size_t need = 2 * (size_t)n_nodes * row_bytes;      // Xh + Agg

    if (ws_size >= need) {
        uint32_t* Xh  = (uint32_t*)d_ws;
        uint32_t* Agg = (uint32_t*)((char*)d_ws + (size_t)n_nodes * row_bytes);

        const long n4 = (long)n_nodes * (D / 4);
        int cast_blocks = (int)((n4 + 255) / 256);
        if (cast_blocks > 6400) cast_blocks = 6400;
        cast_kernel<<<cast_blocks, 256, 0, stream>>>(X, Xh, n4);

        const int gather_blocks = (((n_nodes + 1) / 2) + 3) / 4;  // 2 rows/wave, 4 waves/block
        gather2_kernel<<<gather_blocks, 256, 0, stream>>>(Xh, rp, ci, Agg, n_nodes);

        const int n_tiles = (n_nodes + 15) / 16;
        const int gemm_blocks = (n_tiles + 3) / 4;
        agg_gemm_kernel<<<gemm_blocks, 256, 0, stream>>>(Agg, W, out, n_nodes);
    } else {
        fused_kernel<<<2048, 256, 0, stream>>>(X, W, rp, ci, out, n_nodes);
    }
}

// Round 7
// 146.272 us; speedup vs baseline: 1.1436x; 1.0553x over previous
//
#include <hip/hip_runtime.h>
#include <cstdint>
#include <cstddef>

#define D 64

typedef float    f32x4 __attribute__((ext_vector_type(4)));
typedef short    s16x8 __attribute__((ext_vector_type(8)));
typedef uint32_t u32x4 __attribute__((ext_vector_type(4)));

// round-to-nearest-even fp32 -> bf16 (bits in low 16)
__device__ __forceinline__ uint32_t rne_bf16(float f) {
    uint32_t x = __float_as_uint(f);
    return (x + 0x7fffu + ((x >> 16) & 1u)) >> 16;
}
__device__ __forceinline__ float bf16lo(uint32_t u) { return __uint_as_float(u << 16); }
__device__ __forceinline__ float bf16hi(uint32_t u) { return __uint_as_float(u & 0xffff0000u); }

// Kernel 1: Xh = packed bf16(X). u32 t of a row packs features (2t, 2t+1).
__global__ __launch_bounds__(256) void cast_kernel(
    const float* __restrict__ X, uint32_t* __restrict__ Xh, long n4)
{
    long i = (long)blockIdx.x * blockDim.x + threadIdx.x;
    const long stride = (long)gridDim.x * blockDim.x;
    for (; i < n4; i += stride) {
        f32x4 v = __builtin_nontemporal_load((const f32x4*)X + i);
        uint2 o;
        o.x = rne_bf16(v.x) | (rne_bf16(v.y) << 16);
        o.y = rne_bf16(v.z) | (rne_bf16(v.w) << 16);
        ((uint2*)Xh)[i] = o;
    }
}

// Kernel 2: Agg[r] = bf16( sum_{e in row r} Xh[ci[e]] ).
// ONE row per wave. o = lane>>3 (edge slot 0..7), p = lane&7 (feature octet,
// uint4 = 8 bf16 = full 128B row across 8 lanes). 8 edges per load instr.
// Main iter = 32 edges: 4 independent idx loads then 4 independent gathers
// -> up to 8 loads in flight per wave.
__global__ __launch_bounds__(256) void gather3_kernel(
    const uint32_t* __restrict__ Xh, const int* __restrict__ rp,
    const int* __restrict__ ci, uint32_t* __restrict__ Agg, int n_nodes)
{
    const int lane = threadIdx.x & 63;
    const int o = lane >> 3;
    const int p = lane & 7;
    const int row = (int)((blockIdx.x * blockDim.x + threadIdx.x) >> 6);
    if (row >= n_nodes) return;

    const int e0 = rp[row];
    const int e1 = rp[row + 1];

    float a[8] = {0,0,0,0,0,0,0,0};
    float b[8] = {0,0,0,0,0,0,0,0};

    int e = e0;
    // main: 32 edges per iteration, all loads independent
    for (; e + 32 <= e1; e += 32) {
        const int i0 = ci[e      + o];
        const int i1 = ci[e +  8 + o];
        const int i2 = ci[e + 16 + o];
        const int i3 = ci[e + 24 + o];
        const u32x4 u0 = *(const u32x4*)(Xh + (size_t)i0 * 32 + p * 4);
        const u32x4 u1 = *(const u32x4*)(Xh + (size_t)i1 * 32 + p * 4);
        const u32x4 u2 = *(const u32x4*)(Xh + (size_t)i2 * 32 + p * 4);
        const u32x4 u3 = *(const u32x4*)(Xh + (size_t)i3 * 32 + p * 4);
#pragma unroll
        for (int k = 0; k < 4; ++k) {
            a[2*k] += bf16lo(u0[k]); a[2*k+1] += bf16hi(u0[k]);
            b[2*k] += bf16lo(u1[k]); b[2*k+1] += bf16hi(u1[k]);
            a[2*k] += bf16lo(u2[k]); a[2*k+1] += bf16hi(u2[k]);
            b[2*k] += bf16lo(u3[k]); b[2*k+1] += bf16hi(u3[k]);
        }
    }
    // 16-edge step
    if (e + 16 <= e1) {
        const int i0 = ci[e     + o];
        const int i1 = ci[e + 8 + o];
        const u32x4 u0 = *(const u32x4*)(Xh + (size_t)i0 * 32 + p * 4);
        const u32x4 u1 = *(const u32x4*)(Xh + (size_t)i1 * 32 + p * 4);
#pragma unroll
        for (int k = 0; k < 4; ++k) {
            a[2*k] += bf16lo(u0[k]); a[2*k+1] += bf16hi(u0[k]);
            b[2*k] += bf16lo(u1[k]); b[2*k+1] += bf16hi(u1[k]);
        }
        e += 16;
    }
    // 8-edge step
    if (e + 8 <= e1) {
        const int i0 = ci[e + o];
        const u32x4 u0 = *(const u32x4*)(Xh + (size_t)i0 * 32 + p * 4);
#pragma unroll
        for (int k = 0; k < 4; ++k) {
            a[2*k] += bf16lo(u0[k]); a[2*k+1] += bf16hi(u0[k]);
        }
        e += 8;
    }
    // final 0..7 edges, predicated over o
    if (o < e1 - e) {
        const int i0 = ci[e + o];
        const u32x4 u0 = *(const u32x4*)(Xh + (size_t)i0 * 32 + p * 4);
#pragma unroll
        for (int k = 0; k < 4; ++k) {
            b[2*k] += bf16lo(u0[k]); b[2*k+1] += bf16hi(u0[k]);
        }
    }

    // reduce across the 8 edge slots (bits 3..5 of lane); lanes 0..7 get sums
#pragma unroll
    for (int j = 0; j < 8; ++j) {
        float v = a[j] + b[j];
        v += __shfl_xor(v, 8, 64);
        v += __shfl_xor(v, 16, 64);
        v += __shfl_xor(v, 32, 64);
        a[j] = v;
    }
    if (lane < 8) {
        u32x4 w;
#pragma unroll
        for (int k = 0; k < 4; ++k)
            w[k] = rne_bf16(a[2*k]) | (rne_bf16(a[2*k+1]) << 16);
        *(u32x4*)(Agg + (size_t)row * 32 + p * 4) = w;  // 8 lanes x 16B = 128B
    }
}

// Kernel 3: out = Agg(bf16) @ W via mfma_f32_16x16x32_bf16.
// One wave per 16-row tile (grid-strided). B-frags (W) in VGPRs per wave.
// A-frag: A[m=lane&15][k=q*8+j]; B-frag: B[k=q*8+j][n=lane&15];
// C/D: col=lane&15, row=q*4+reg  (q = lane>>4).
__global__ __launch_bounds__(256) void agg_gemm_kernel(
    const uint32_t* __restrict__ Agg, const float* __restrict__ W,
    float* __restrict__ out, int n_nodes)
{
    const int lane = threadIdx.x & 63;
    const int n = lane & 15;
    const int q = lane >> 4;

    s16x8 Bf[4][2];
#pragma unroll
    for (int c = 0; c < 4; ++c)
#pragma unroll
        for (int kb = 0; kb < 2; ++kb) {
            s16x8 bfr;
#pragma unroll
            for (int j = 0; j < 8; ++j) {
                const int k = kb * 32 + q * 8 + j;
                bfr[j] = (short)rne_bf16(W[k * D + c * 16 + n]);
            }
            Bf[c][kb] = bfr;
        }

    const int n_tiles = (n_nodes + 15) / 16;
    const int gwave = (int)((blockIdx.x * blockDim.x + threadIdx.x) >> 6);
    const int nwaves = (int)((gridDim.x * blockDim.x) >> 6);

    for (int t = gwave; t < n_tiles; t += nwaves) {
        const int m0 = t * 16;
        int arow = m0 + n;
        if (arow >= n_nodes) arow = n_nodes - 1;  // clamp (tail tile)
        const s16x8 A0 = *(const s16x8*)(Agg + (size_t)arow * 32 + q * 4);
        const s16x8 A1 = *(const s16x8*)(Agg + (size_t)arow * 32 + 16 + q * 4);

        f32x4 acc[4];
#pragma unroll
        for (int c = 0; c < 4; ++c) {
            f32x4 z = {0.f, 0.f, 0.f, 0.f};
            z = __builtin_amdgcn_mfma_f32_16x16x32_bf16(A0, Bf[c][0], z, 0, 0, 0);
            z = __builtin_amdgcn_mfma_f32_16x16x32_bf16(A1, Bf[c][1], z, 0, 0, 0);
            acc[c] = z;
        }
#pragma unroll
        for (int r = 0; r < 4; ++r) {
            const int ro = m0 + q * 4 + r;
            if (ro < n_nodes) {
#pragma unroll
                for (int c = 0; c < 4; ++c)
                    out[(size_t)ro * D + c * 16 + n] = acc[c][r];
            }
        }
    }
}

// Fallback if ws can't hold Xh+Agg: fused per-row aggregate + shfl GEMM.
__global__ __launch_bounds__(256) void fused_kernel(
    const float* __restrict__ X, const float* __restrict__ W,
    const int* __restrict__ rp, const int* __restrict__ ci,
    float* __restrict__ out, int n_nodes)
{
    __shared__ float Wl[D * D];
    for (int i = threadIdx.x; i < D * D; i += 256) Wl[i] = W[i];
    __syncthreads();

    const int lane = threadIdx.x & 63;
    const int gwave = (int)((blockIdx.x * blockDim.x + threadIdx.x) >> 6);
    const int nwaves = (int)((gridDim.x * blockDim.x) >> 6);

    for (int row = gwave; row < n_nodes; row += nwaves) {
        int e0 = rp[row];
        int e1 = rp[row + 1];
        float acc = 0.f;
        for (int e = e0; e < e1; ++e) acc += X[ci[e] * D + lane];
        float sum = 0.f;
#pragma unroll
        for (int d = 0; d < D; ++d) {
            float a = __shfl(acc, d, 64);
            sum += a * Wl[d * D + lane];
        }
        out[row * D + lane] = sum;
    }
}

extern "C" void kernel_launch(void* const* d_in, const int* in_sizes, int n_in,
                              void* d_out, int out_size, void* d_ws, size_t ws_size,
                              hipStream_t stream)
{
    const float* X  = (const float*)d_in[0];   // [n, 64]
    const float* W  = (const float*)d_in[1];   // [64, 64]
    const int*   rp = (const int*)d_in[2];     // [n+1]
    const int*   ci = (const int*)d_in[3];     // [n_edges]
    float* out = (float*)d_out;

    const int n_nodes = in_sizes[2] - 1;
    const size_t row_bytes = 32 * sizeof(uint32_t);           // 128 B bf16 row
    const size_t need = 2 * (size_t)n_nodes * row_bytes;      // Xh + Agg

    if (ws_size >= need) {
        uint32_t* Xh  = (uint32_t*)d_ws;
        uint32_t* Agg = (uint32_t*)((char*)d_ws + (size_t)n_nodes * row_bytes);

        const long n4 = (long)n_nodes * (D / 4);
        int cast_blocks = (int)((n4 + 255) / 256);
        if (cast_blocks > 6400) cast_blocks = 6400;
        cast_kernel<<<cast_blocks, 256, 0, stream>>>(X, Xh, n4);

        const int gather_blocks = (n_nodes + 3) / 4;  // 1 row/wave, 4 waves/block
        gather3_kernel<<<gather_blocks, 256, 0, stream>>>(Xh, rp, ci, Agg, n_nodes);

        const int n_tiles = (n_nodes + 15) / 16;
        const int gemm_blocks = (n_tiles + 3) / 4;
        agg_gemm_kernel<<<gemm_blocks, 256, 0, stream>>>(Agg, W, out, n_nodes);
    } else {
        fused_kernel<<<2048, 256, 0, stream>>>(X, W, rp, ci, out, n_nodes);
    }
}